// Round 1
// baseline (2040.553 us; speedup 1.0000x reference)
//
#include <hip/hip_runtime.h>
#include <hip/hip_fp16.h>

#define K_NB 8
#define NV   6890
#define NQ   32768
#define DF   64
#define DIN  67
#define DH   128

// ---- workspace layout (assumes ws_size >= ~2.3 MB) ----
static constexpr size_t VTX4_BYTES = 110592;                 // NV*16 = 110240, padded
static constexpr size_t KIDX_OFF   = VTX4_BYTES;
static constexpr size_t KIDX_BYTES = (size_t)NQ * 8 * 4;
static constexpr size_t KW_OFF     = KIDX_OFF + KIDX_BYTES;  // float[NQ*8]

// Pack vertex -> {x, y, z, 0.5*|v|^2} so knn score = 0.5|v|^2 - q.v  (3 FMAs)
__global__ void prep_kernel(const float* __restrict__ vtx, float4* __restrict__ vtx4) {
    int i = blockIdx.x * blockDim.x + threadIdx.x;
    if (i < NV) {
        float x = vtx[i * 3 + 0], y = vtx[i * 3 + 1], z = vtx[i * 3 + 2];
        vtx4[i] = make_float4(x, y, z, 0.5f * (x * x + y * y + z * z));
    }
}

// One query per thread. Vertex loads are wave-uniform -> scalar loads.
__global__ __launch_bounds__(64) void knn_kernel(const float4* __restrict__ vtx4,
                                                 const float* __restrict__ qpts,
                                                 int* __restrict__ kidx,
                                                 float* __restrict__ kw) {
    int m = blockIdx.x * 64 + threadIdx.x;
    float qx = qpts[m * 3 + 0], qy = qpts[m * 3 + 1], qz = qpts[m * 3 + 2];
    float nqx = -qx, nqy = -qy, nqz = -qz;

    float best[8];
    int   bidx[8];
#pragma unroll
    for (int i = 0; i < 8; ++i) { best[i] = 3.0e38f; bidx[i] = 0; }

#pragma unroll 4
    for (int j = 0; j < NV; ++j) {
        float4 v = vtx4[j];                 // uniform across lanes -> s_load
        float  s = fmaf(nqx, v.x, v.w);
        s = fmaf(nqy, v.y, s);
        s = fmaf(nqz, v.z, s);
        if (s < best[7]) {                  // rare after warm-up
            // branchless sorted insert (ascending)
#pragma unroll
            for (int i = 7; i > 0; --i) {
                bool  sh = s < best[i - 1];
                float nb = sh ? best[i - 1] : fminf(s, best[i]);
                int   ni = sh ? bidx[i - 1] : ((s < best[i]) ? j : bidx[i]);
                best[i] = nb; bidx[i] = ni;
            }
            if (s < best[0]) { best[0] = s; bidx[0] = j; }
        }
    }

    // d2 = 2*s + |q|^2  (matches reference's expanded form in fp32)
    float q2 = fmaf(qx, qx, fmaf(qy, qy, qz * qz));
    float inv[8], ssum = 0.0f;
#pragma unroll
    for (int i = 0; i < 8; ++i) {
        float d2 = fmaf(2.0f, best[i], q2);
        float d  = sqrtf(fmaxf(d2, 0.0f)) + 1e-9f;
        inv[i] = 1.0f / d;
        ssum  += inv[i];
    }
    float rs = 1.0f / ssum;
#pragma unroll
    for (int i = 0; i < 8; ++i) {
        kidx[m * 8 + i] = bidx[i];
        kw[m * 8 + i]   = inv[i] * rs;
    }
}

// One layer: in (transposed f16 LDS [k][row]) -> out, fp32 accumulate,
// weights via wave-uniform scalar loads from global (L2-resident).
template <int KD, int CD, bool RELU>
__device__ __forceinline__ void run_layer(const _Float16 (*in)[256], _Float16 (*outb)[256],
                                          const float* __restrict__ W,
                                          const float* __restrict__ B, int r) {
#pragma unroll 1
    for (int cg = 0; cg < CD / 16; ++cg) {
        int   c0 = cg * 16;
        float acc[16];
#pragma unroll
        for (int j = 0; j < 16; ++j) acc[j] = B[c0 + j];
#pragma unroll 2
        for (int k = 0; k < KD; ++k) {
            float        xv = (float)in[k][r];
            const float* wr = W + k * CD + c0;   // uniform -> s_load_dwordx8
#pragma unroll
            for (int j = 0; j < 16; ++j) acc[j] = fmaf(xv, wr[j], acc[j]);
        }
#pragma unroll
        for (int j = 0; j < 16; ++j) {
            float v = RELU ? fmaxf(acc[j], 0.0f) : acc[j];
            outb[c0 + j][r] = (_Float16)v;
        }
    }
}

// Block = 256 rows = 32 queries x 8 neighbors. Activations f16, transposed in LDS.
__global__ __launch_bounds__(256) void mlp_kernel(
    const float* __restrict__ vf, const float4* __restrict__ vtx4,
    const float* __restrict__ qpts,
    const int* __restrict__ kidx, const float* __restrict__ kw,
    const float* __restrict__ W0, const float* __restrict__ b0,
    const float* __restrict__ W1, const float* __restrict__ b1,
    const float* __restrict__ W2, const float* __restrict__ b2,
    const float* __restrict__ W3, const float* __restrict__ b3,
    float* __restrict__ out) {
    __shared__ _Float16 A0[DH][256];   // 64 KB
    __shared__ _Float16 A1[DH][256];   // 64 KB

    int   r    = threadIdx.x;
    int   grow = blockIdx.x * 256 + r;      // global row (query*8 + k)
    int   q    = grow >> 3;
    int   idx  = kidx[grow];
    float wgt  = kw[grow];

    // ---- stage X = [features(64) | q - v(3)] into A0 (transposed) ----
    const float4* f4 = (const float4*)(vf + (size_t)idx * DF);
#pragma unroll
    for (int t = 0; t < 16; ++t) {
        float4 v = f4[t];
        A0[4 * t + 0][r] = (_Float16)v.x;
        A0[4 * t + 1][r] = (_Float16)v.y;
        A0[4 * t + 2][r] = (_Float16)v.z;
        A0[4 * t + 3][r] = (_Float16)v.w;
    }
    {
        float4 v  = vtx4[idx];
        float  qx = qpts[q * 3 + 0], qy = qpts[q * 3 + 1], qz = qpts[q * 3 + 2];
        A0[64][r] = (_Float16)(qx - v.x);
        A0[65][r] = (_Float16)(qy - v.y);
        A0[66][r] = (_Float16)(qz - v.z);
    }
    __syncthreads();

    run_layer<DIN, DH, true>(A0, A1, W0, b0, r);
    __syncthreads();
    run_layer<DH, DH, true>(A1, A0, W1, b1, r);
    __syncthreads();
    run_layer<DH, DH, true>(A0, A1, W2, b2, r);
    __syncthreads();

    // ---- L3: A1(128) -> 64 cols, weight, reduce over 8 neighbor lanes ----
#pragma unroll 1
    for (int cg = 0; cg < 4; ++cg) {
        int   c0 = cg * 16;
        float acc[16];
#pragma unroll
        for (int j = 0; j < 16; ++j) acc[j] = b3[c0 + j];
#pragma unroll 2
        for (int k = 0; k < DH; ++k) {
            float        xv = (float)A1[k][r];
            const float* wr = W3 + k * 64 + c0;
#pragma unroll
            for (int j = 0; j < 16; ++j) acc[j] = fmaf(xv, wr[j], acc[j]);
        }
#pragma unroll
        for (int j = 0; j < 16; ++j) {
            float v = acc[j] * wgt;
            v += __shfl_xor(v, 1, 8);
            v += __shfl_xor(v, 2, 8);
            v += __shfl_xor(v, 4, 8);
            acc[j] = v;
        }
        if ((r & 7) == 0) {
            float4* dst = (float4*)(out + (size_t)q * 64 + c0);
            dst[0] = make_float4(acc[0], acc[1], acc[2], acc[3]);
            dst[1] = make_float4(acc[4], acc[5], acc[6], acc[7]);
            dst[2] = make_float4(acc[8], acc[9], acc[10], acc[11]);
            dst[3] = make_float4(acc[12], acc[13], acc[14], acc[15]);
        }
    }
}

extern "C" void kernel_launch(void* const* d_in, const int* in_sizes, int n_in,
                              void* d_out, int out_size, void* d_ws, size_t ws_size,
                              hipStream_t stream) {
    const float* vtx = (const float*)d_in[0];
    const float* vf  = (const float*)d_in[1];
    const float* qp  = (const float*)d_in[2];
    const float* W0  = (const float*)d_in[3];
    const float* b0  = (const float*)d_in[4];
    const float* W1  = (const float*)d_in[5];
    const float* b1  = (const float*)d_in[6];
    const float* W2  = (const float*)d_in[7];
    const float* b2  = (const float*)d_in[8];
    const float* W3  = (const float*)d_in[9];
    const float* b3  = (const float*)d_in[10];
    float*       out = (float*)d_out;

    char*   ws   = (char*)d_ws;
    float4* vtx4 = (float4*)ws;
    int*    kidx = (int*)(ws + KIDX_OFF);
    float*  kw   = (float*)(ws + KW_OFF);

    hipLaunchKernelGGL(prep_kernel, dim3((NV + 255) / 256), dim3(256), 0, stream, vtx, vtx4);
    hipLaunchKernelGGL(knn_kernel, dim3(NQ / 64), dim3(64), 0, stream, vtx4, qp, kidx, kw);
    hipLaunchKernelGGL(mlp_kernel, dim3(NQ * 8 / 256), dim3(256), 0, stream,
                       vf, vtx4, qp, kidx, kw, W0, b0, W1, b1, W2, b2, W3, b3, out);
}

// Round 4
// 419.369 us; speedup vs baseline: 4.8658x; 4.8658x over previous
//
#include <hip/hip_runtime.h>
#include <hip/hip_fp16.h>

#define NV   6890
#define NQ   32768
#define DF   64
#define DH   128

typedef _Float16 v8h  __attribute__((ext_vector_type(8)));
typedef float    f32x4 __attribute__((ext_vector_type(4)));

// ---- workspace layout (bytes) ----
static constexpr size_t VTX4_OFF  = 0;                       // float4[6912]
static constexpr size_t KIDX_OFF  = 110592;
static constexpr size_t KW_OFF    = KIDX_OFF + (size_t)NQ * 8 * 4;   // 1159168
static constexpr size_t WFRAG_OFF = KW_OFF + (size_t)NQ * 8 * 4;     // 2207744
// wfrag (f16 elems): L0 @0 (12288), L1 @12288 (16384), L2 @28672 (16384), L3 @45056 (8192)

#define INSERT8(sv, jv) do {                                          \
    if ((sv) < best[7]) {                                             \
        _Pragma("unroll")                                             \
        for (int i = 7; i > 0; --i) {                                 \
            bool  sh = (sv) < best[i - 1];                            \
            float nb = sh ? best[i - 1] : fminf((sv), best[i]);       \
            int   ni = sh ? bidx[i - 1] : (((sv) < best[i]) ? (jv) : bidx[i]); \
            best[i] = nb; bidx[i] = ni;                               \
        }                                                             \
        if ((sv) < best[0]) { best[0] = (sv); bidx[0] = (jv); }       \
    }                                                                 \
} while (0)

// prep: pack vertices {x,y,z,0.5|v|^2} AND pre-swizzle weights into per-lane
// MFMA fragment order (f16). Fragment map: tile t=kt*NCT+ct, elem = t*512+lane*8+j,
// k = kt*32+(lane>>4)*8+j, col = ct*16+(lane&15).
__global__ void prep_kernel(const float* __restrict__ vtx, float4* __restrict__ vtx4,
                            const float* __restrict__ W0, const float* __restrict__ W1,
                            const float* __restrict__ W2, const float* __restrict__ W3,
                            _Float16* __restrict__ wfrag) {
    int b = blockIdx.x;
    if (b < 27) {
        int i = b * 256 + threadIdx.x;
        if (i < NV) {
            float x = vtx[i * 3 + 0], y = vtx[i * 3 + 1], z = vtx[i * 3 + 2];
            vtx4[i] = make_float4(x, y, z, 0.5f * (x * x + y * y + z * z));
        }
        return;
    }
    int e = (b - 27) * 256 + threadIdx.x;   // 0..53247
    const float* W; int base, NCT, C, KD;
    if      (e < 12288) { W = W0; base = 0;     NCT = 8; C = 128; KD = 67;  }
    else if (e < 28672) { W = W1; base = 12288; NCT = 8; C = 128; KD = 128; }
    else if (e < 45056) { W = W2; base = 28672; NCT = 8; C = 128; KD = 128; }
    else                { W = W3; base = 45056; NCT = 4; C = 64;  KD = 128; }
    int le = e - base;
    int t = le >> 9, r = le & 511;
    int lane = r >> 3, j = r & 7;
    int kt = t / NCT, ct = t % NCT;
    int k = kt * 32 + (lane >> 4) * 8 + j;
    int col = ct * 16 + (lane & 15);
    float v = (k < KD) ? W[k * C + col] : 0.0f;
    wfrag[e] = (_Float16)v;
}

// knn: 64 queries/block, 8 waves split the vertex range, LDS merge by wave 0.
__global__ __launch_bounds__(512) void knn_kernel(const float4* __restrict__ vtx4,
                                                  const float* __restrict__ qpts,
                                                  int* __restrict__ kidx,
                                                  float* __restrict__ kw) {
    __shared__ float ps[8][64][8];
    __shared__ int   pi[8][64][8];
    int tid = threadIdx.x, w = tid >> 6, l = tid & 63;
    int m = blockIdx.x * 64 + l;
    float qx = qpts[m * 3 + 0], qy = qpts[m * 3 + 1], qz = qpts[m * 3 + 2];
    float nqx = -qx, nqy = -qy, nqz = -qz;

    float best[8]; int bidx[8];
#pragma unroll
    for (int i = 0; i < 8; ++i) { best[i] = 3.0e38f; bidx[i] = 0; }

    int j0 = w * 862, j1 = (j0 + 862 < NV) ? j0 + 862 : NV;
#pragma unroll 2
    for (int j = j0; j < j1; ++j) {
        float4 v = vtx4[j];                       // wave-uniform -> s_load
        float  s = fmaf(nqx, v.x, v.w);
        s = fmaf(nqy, v.y, s);
        s = fmaf(nqz, v.z, s);
        INSERT8(s, j);
    }
#pragma unroll
    for (int i = 0; i < 8; ++i) { ps[w][l][i] = best[i]; pi[w][l][i] = bidx[i]; }
    __syncthreads();

    if (tid < 64) {
#pragma unroll
        for (int i = 0; i < 8; ++i) { best[i] = 3.0e38f; bidx[i] = 0; }
#pragma unroll 1
        for (int ww = 0; ww < 8; ++ww)
#pragma unroll 1
            for (int e = 0; e < 8; ++e) {
                float s = ps[ww][tid][e];
                if (s < best[7]) { int jj = pi[ww][tid][e]; INSERT8(s, jj); }
            }
        float q2 = fmaf(qx, qx, fmaf(qy, qy, qz * qz));
        float inv[8], ssum = 0.0f;
#pragma unroll
        for (int i = 0; i < 8; ++i) {
            float d2 = fmaf(2.0f, best[i], q2);
            float d  = sqrtf(fmaxf(d2, 0.0f)) + 1e-9f;
            inv[i] = 1.0f / d;
            ssum  += inv[i];
        }
        float rs = 1.0f / ssum;
#pragma unroll
        for (int i = 0; i < 8; ++i) {
            kidx[m * 8 + i] = bidx[i];
            kw[m * 8 + i]   = inv[i] * rs;
        }
    }
}

// One MLP layer on this wave's 32 rows, in-place in buf. A-frag: row=l&15(+16*rt),
// k=(l>>4)*8+j; B-frag preswizzled with the SAME (lane,j)->k map (k-perm cancels).
template <int KSTEPS, int NCT, bool RELU>
__device__ __forceinline__ void mlp_layer(_Float16 (*buf)[136],
                                          const _Float16* __restrict__ frag,
                                          const float* __restrict__ bias,
                                          int w, int l) {
    const int cl = l & 15, gl = l >> 4;
    f32x4 acc[2][NCT];
#pragma unroll
    for (int ct = 0; ct < NCT; ++ct) {
        float bv = bias[ct * 16 + cl];
#pragma unroll
        for (int rt = 0; rt < 2; ++rt) acc[rt][ct] = (f32x4){bv, bv, bv, bv};
    }
    const _Float16* fb = frag + (size_t)l * 8;
#pragma unroll 1
    for (int ks = 0; ks < KSTEPS; ++ks) {
        v8h a0 = *(const v8h*)&buf[w * 32 + cl][ks * 32 + gl * 8];
        v8h a1 = *(const v8h*)&buf[w * 32 + 16 + cl][ks * 32 + gl * 8];
#pragma unroll
        for (int ct = 0; ct < NCT; ++ct) {
            v8h bf = *(const v8h*)(fb + (size_t)(ks * NCT + ct) * 512);
            acc[0][ct] = __builtin_amdgcn_mfma_f32_16x16x32_f16(a0, bf, acc[0][ct], 0, 0, 0);
            acc[1][ct] = __builtin_amdgcn_mfma_f32_16x16x32_f16(a1, bf, acc[1][ct], 0, 0, 0);
        }
    }
    // C/D layout (m89-verified): row=(l>>4)*4+j, col=l&15
#pragma unroll
    for (int rt = 0; rt < 2; ++rt)
#pragma unroll
        for (int ct = 0; ct < NCT; ++ct)
#pragma unroll
            for (int j = 0; j < 4; ++j) {
                float v = acc[rt][ct][j];
                if (RELU) v = fmaxf(v, 0.0f);
                buf[w * 32 + rt * 16 + gl * 4 + j][ct * 16 + cl] = (_Float16)v;
            }
}

// Block = 128 rows (16 queries x 8 NB), 4 waves, each wave owns 32 rows.
// No __syncthreads anywhere: all LDS traffic is wave-private.
__global__ __launch_bounds__(256, 3) void mlp_kernel(
    const float* __restrict__ vf, const float4* __restrict__ vtx4,
    const float* __restrict__ qpts,
    const int* __restrict__ kidx, const float* __restrict__ kw,
    const _Float16* __restrict__ wfrag,
    const float* __restrict__ b0, const float* __restrict__ b1,
    const float* __restrict__ b2, const float* __restrict__ b3,
    float* __restrict__ out) {
    __shared__ _Float16 buf[128][136];   // 34.8 KB, stride 136 -> b128 reads 2-way (free)
    const int tid = threadIdx.x, w = tid >> 6, l = tid & 63;

    // ---- stage X = [feat(64) | q-v(3) | zeros..95] for rows w*32..w*32+31 ----
    {
        int h = l & 1;
        int lrow = w * 32 + (l >> 1);
        int grow = blockIdx.x * 128 + lrow;
        int q = grow >> 3;
        int idx = kidx[grow];
        const float4* src = (const float4*)(vf + (size_t)idx * DF) + h * 8;
#pragma unroll
        for (int t = 0; t < 4; ++t) {
            float4 a = src[2 * t], b = src[2 * t + 1];
            v8h pk = {(_Float16)a.x, (_Float16)a.y, (_Float16)a.z, (_Float16)a.w,
                      (_Float16)b.x, (_Float16)b.y, (_Float16)b.z, (_Float16)b.w};
            *(v8h*)&buf[lrow][h * 32 + t * 8] = pk;
        }
        v8h zz = {0, 0, 0, 0, 0, 0, 0, 0};
        if (h == 0) {
            float4 v = vtx4[idx];
            float qx = qpts[q * 3 + 0], qy = qpts[q * 3 + 1], qz = qpts[q * 3 + 2];
            v8h d = {(_Float16)(qx - v.x), (_Float16)(qy - v.y), (_Float16)(qz - v.z),
                     0, 0, 0, 0, 0};
            *(v8h*)&buf[lrow][64] = d;
            *(v8h*)&buf[lrow][88] = zz;
        } else {
            *(v8h*)&buf[lrow][72] = zz;
            *(v8h*)&buf[lrow][80] = zz;
        }
    }

    mlp_layer<3, 8, true>(buf, wfrag + 0,     b0, w, l);
    mlp_layer<4, 8, true>(buf, wfrag + 12288, b1, w, l);
    mlp_layer<4, 8, true>(buf, wfrag + 28672, b2, w, l);

    // ---- layer 3 (K=128 -> 64 cols) + inverse-distance weighting + 8-row reduce ----
    {
        const int cl = l & 15, gl = l >> 4;
        f32x4 acc[2][4];
#pragma unroll
        for (int ct = 0; ct < 4; ++ct) {
            float bv = b3[ct * 16 + cl];
#pragma unroll
            for (int rt = 0; rt < 2; ++rt) acc[rt][ct] = (f32x4){bv, bv, bv, bv};
        }
        const _Float16* fb = wfrag + 45056 + (size_t)l * 8;
#pragma unroll 1
        for (int ks = 0; ks < 4; ++ks) {
            v8h a0 = *(const v8h*)&buf[w * 32 + cl][ks * 32 + gl * 8];
            v8h a1 = *(const v8h*)&buf[w * 32 + 16 + cl][ks * 32 + gl * 8];
#pragma unroll
            for (int ct = 0; ct < 4; ++ct) {
                v8h bf = *(const v8h*)(fb + (size_t)(ks * 4 + ct) * 512);
                acc[0][ct] = __builtin_amdgcn_mfma_f32_16x16x32_f16(a0, bf, acc[0][ct], 0, 0, 0);
                acc[1][ct] = __builtin_amdgcn_mfma_f32_16x16x32_f16(a1, bf, acc[1][ct], 0, 0, 0);
            }
        }
        int GRbase = blockIdx.x * 128 + w * 32;
#pragma unroll
        for (int rt = 0; rt < 2; ++rt) {
            int r4 = GRbase + rt * 16 + gl * 4;       // first of this lane's 4 rows
            float4 kv = *(const float4*)&kw[r4];
#pragma unroll
            for (int ct = 0; ct < 4; ++ct) {
                float v = acc[rt][ct][0] * kv.x + acc[rt][ct][1] * kv.y +
                          acc[rt][ct][2] * kv.z + acc[rt][ct][3] * kv.w;
                v += __shfl_xor(v, 16);               // rows 0-3 + 4-7  (and 8-11 + 12-15)
                if ((gl & 1) == 0) {
                    int q = (GRbase + rt * 16 + ((gl == 2) ? 8 : 0)) >> 3;
                    out[(size_t)q * 64 + ct * 16 + cl] = v;
                }
            }
        }
    }
}

extern "C" void kernel_launch(void* const* d_in, const int* in_sizes, int n_in,
                              void* d_out, int out_size, void* d_ws, size_t ws_size,
                              hipStream_t stream) {
    const float* vtx = (const float*)d_in[0];
    const float* vf  = (const float*)d_in[1];
    const float* qp  = (const float*)d_in[2];
    const float* W0  = (const float*)d_in[3];
    const float* b0  = (const float*)d_in[4];
    const float* W1  = (const float*)d_in[5];
    const float* b1  = (const float*)d_in[6];
    const float* W2  = (const float*)d_in[7];
    const float* b2  = (const float*)d_in[8];
    const float* W3  = (const float*)d_in[9];
    const float* b3  = (const float*)d_in[10];
    float*       out = (float*)d_out;

    char*      ws    = (char*)d_ws;
    float4*    vtx4  = (float4*)(ws + VTX4_OFF);
    int*       kidx  = (int*)(ws + KIDX_OFF);
    float*     kw    = (float*)(ws + KW_OFF);
    _Float16*  wfrag = (_Float16*)(ws + WFRAG_OFF);

    hipLaunchKernelGGL(prep_kernel, dim3(27 + 208), dim3(256), 0, stream,
                       vtx, vtx4, W0, W1, W2, W3, wfrag);
    hipLaunchKernelGGL(knn_kernel, dim3(NQ / 64), dim3(512), 0, stream, vtx4, qp, kidx, kw);
    hipLaunchKernelGGL(mlp_kernel, dim3(NQ * 8 / 128), dim3(256), 0, stream,
                       vf, vtx4, qp, kidx, kw, wfrag, b0, b1, b2, b3, out);
}

// Round 6
// 228.432 us; speedup vs baseline: 8.9329x; 1.8359x over previous
//
#include <hip/hip_runtime.h>
#include <hip/hip_fp16.h>

#define NV   6890
#define NQ   32768
#define DF   64
#define DH   128
#define CAP  24

typedef _Float16 v8h  __attribute__((ext_vector_type(8)));
typedef float    f32x4 __attribute__((ext_vector_type(4)));

// ---- workspace layout (bytes) ----
static constexpr size_t VTX4_OFF  = 0;                       // float4[6912]
static constexpr size_t KIDX_OFF  = 110592;
static constexpr size_t KW_OFF    = KIDX_OFF + (size_t)NQ * 8 * 4;   // 1159168
static constexpr size_t WFRAG_OFF = KW_OFF + (size_t)NQ * 8 * 4;     // 2207744
// wfrag (f16 elems): L0 @0 (12288), L1 @12288 (16384), L2 @28672 (16384), L3 @45056 (8192)

// Branchless sorted insert (ascending). ~40 VALU ops. All compares precomputed
// so updates use OLD neighbor values.
#define BINSERT(sv, jv) do {                                           \
    bool c0 = (sv) < best[0], c1 = (sv) < best[1],                     \
         c2 = (sv) < best[2], c3 = (sv) < best[3],                     \
         c4 = (sv) < best[4], c5 = (sv) < best[5],                     \
         c6 = (sv) < best[6], c7 = (sv) < best[7];                     \
    best[7] = c7 ? (c6 ? best[6] : (sv)) : best[7];                    \
    bidx[7] = c7 ? (c6 ? bidx[6] : (jv)) : bidx[7];                    \
    best[6] = c6 ? (c5 ? best[5] : (sv)) : best[6];                    \
    bidx[6] = c6 ? (c5 ? bidx[5] : (jv)) : bidx[6];                    \
    best[5] = c5 ? (c4 ? best[4] : (sv)) : best[5];                    \
    bidx[5] = c5 ? (c4 ? bidx[4] : (jv)) : bidx[5];                    \
    best[4] = c4 ? (c3 ? best[3] : (sv)) : best[4];                    \
    bidx[4] = c4 ? (c3 ? bidx[3] : (jv)) : bidx[4];                    \
    best[3] = c3 ? (c2 ? best[2] : (sv)) : best[3];                    \
    bidx[3] = c3 ? (c2 ? bidx[2] : (jv)) : bidx[3];                    \
    best[2] = c2 ? (c1 ? best[1] : (sv)) : best[2];                    \
    bidx[2] = c2 ? (c1 ? bidx[1] : (jv)) : bidx[2];                    \
    best[1] = c1 ? (c0 ? best[0] : (sv)) : best[1];                    \
    bidx[1] = c1 ? (c0 ? bidx[0] : (jv)) : bidx[1];                    \
    best[0] = c0 ? (sv) : best[0];                                     \
    bidx[0] = c0 ? (jv) : bidx[0];                                     \
} while (0)

// prep: pack vertices {x,y,z,0.5|v|^2} AND pre-swizzle weights into per-lane
// MFMA fragment order (f16). Fragment map: tile t=kt*NCT+ct, elem = t*512+lane*8+j,
// k = kt*32+(lane>>4)*8+j, col = ct*16+(lane&15).
__global__ void prep_kernel(const float* __restrict__ vtx, float4* __restrict__ vtx4,
                            const float* __restrict__ W0, const float* __restrict__ W1,
                            const float* __restrict__ W2, const float* __restrict__ W3,
                            _Float16* __restrict__ wfrag) {
    int b = blockIdx.x;
    if (b < 27) {
        int i = b * 256 + threadIdx.x;
        if (i < NV) {
            float x = vtx[i * 3 + 0], y = vtx[i * 3 + 1], z = vtx[i * 3 + 2];
            vtx4[i] = make_float4(x, y, z, 0.5f * (x * x + y * y + z * z));
        }
        return;
    }
    int e = (b - 27) * 256 + threadIdx.x;   // 0..53247
    const float* W; int base, NCT, C, KD;
    if      (e < 12288) { W = W0; base = 0;     NCT = 8; C = 128; KD = 67;  }
    else if (e < 28672) { W = W1; base = 12288; NCT = 8; C = 128; KD = 128; }
    else if (e < 45056) { W = W2; base = 28672; NCT = 8; C = 128; KD = 128; }
    else                { W = W3; base = 45056; NCT = 4; C = 64;  KD = 128; }
    int le = e - base;
    int t = le >> 9, r = le & 511;
    int lane = r >> 3, j = r & 7;
    int kt = t / NCT, ct = t % NCT;
    int k = kt * 32 + (lane >> 4) * 8 + j;
    int col = ct * 16 + (lane & 15);
    float v = (k < KD) ? W[k * C + col] : 0.0f;
    wfrag[e] = (_Float16)v;
}

__device__ __forceinline__ float vdist(const float4 v, float nqx, float nqy, float nqz) {
    float s = fmaf(nqx, v.x, v.w);
    s = fmaf(nqy, v.y, s);
    return fmaf(nqz, v.z, s);
}

// Exact two-phase KNN. Block = 64 queries (one per lane) x 8 waves (vertex chunks).
// Phase A: per-wave 64-vertex prefix -> per-lane top-8.  Phase B: merge the 512
// prefix candidates from LDS -> exact threshold T (8th smallest of prefix).
// Scan: remaining vertices filtered by s<=T into a per-lane u16 queue (cap 24,
// overflow -> inline insert, still exact).  Drain + cross-wave merge + weights.
__global__ __launch_bounds__(512) void knn_kernel(const float4* __restrict__ vtx4,
                                                  const float* __restrict__ qpts,
                                                  int* __restrict__ kidx,
                                                  float* __restrict__ kw) {
    __shared__ float          ps[8][64][9];   // pad 9: conflict-free
    __shared__ int            pi[8][64][9];
    __shared__ unsigned short qq[8][64][CAP];
    const int tid = threadIdx.x, w = tid >> 6, l = tid & 63;
    const int m = blockIdx.x * 64 + l;
    const float qx = qpts[m * 3 + 0], qy = qpts[m * 3 + 1], qz = qpts[m * 3 + 2];
    const float nqx = -qx, nqy = -qy, nqz = -qz;

    float best[8]; int bidx[8];
#pragma unroll
    for (int i = 0; i < 8; ++i) { best[i] = 3.0e38f; bidx[i] = 0; }

    const int base = w * 862;

    // ---- stage A: prefix [base, base+64) ----
#pragma unroll 2
    for (int j = base; j < base + 64; ++j) {
        float s = vdist(vtx4[j], nqx, nqy, nqz);     // wave-uniform -> s_load
        BINSERT(s, j);
    }
#pragma unroll
    for (int i = 0; i < 8; ++i) { ps[w][l][i] = best[i]; pi[w][l][i] = bidx[i]; }
    __syncthreads();

    // ---- stage B: rebuild top-8 of the 512-vertex prefix union -> T ----
#pragma unroll
    for (int i = 0; i < 8; ++i) { best[i] = 3.0e38f; bidx[i] = 0; }
#pragma unroll 1
    for (int ww = 0; ww < 8; ++ww)
#pragma unroll
        for (int e = 0; e < 8; ++e) {
            float s = ps[ww][l][e]; int j = pi[ww][l][e];
            BINSERT(s, j);
        }
    const float T = best[7];
    __syncthreads();                                  // ps/pi reused below

    // only wave 0 seeds from the prefix list (avoids duplicates across waves)
    if (w != 0) {
#pragma unroll
        for (int i = 0; i < 8; ++i) { best[i] = 3.0e38f; bidx[i] = 0; }
    }

    // ---- scan: filter survivors (s<=T) into per-lane queue ----
    int cnt = 0;
    const int j1 = (base + 862 < NV) ? base + 862 : NV;
#pragma unroll 2
    for (int j = base + 64; j < j1; ++j) {
        float s = vdist(vtx4[j], nqx, nqy, nqz);
        if (s <= T) {
            if (cnt < CAP) { qq[w][l][cnt] = (unsigned short)j; ++cnt; }
            else if (s < best[7]) { BINSERT(s, j); }  // overflow fallback (exact)
        }
    }

    // ---- drain queue in batches of 8 (prefetch loads, then insert) ----
    for (int b = 0; b < CAP; b += 8) {
        if (!__any(cnt > b)) break;
        int jj[8]; float4 vv[8];
#pragma unroll
        for (int t = 0; t < 8; ++t) {
            int qi = (b + t < cnt) ? (int)qq[w][l][b + t] : 0;
            jj[t] = qi; vv[t] = vtx4[qi];
        }
#pragma unroll
        for (int t = 0; t < 8; ++t) {
            float s = vdist(vv[t], nqx, nqy, nqz);
            s = (b + t < cnt) ? s : 3.0e38f;          // masked entries never insert
            BINSERT(s, jj[t]);
        }
    }

    // ---- publish per-wave lists; wave 0 merges + weights ----
    if (w != 0) {
#pragma unroll
        for (int i = 0; i < 8; ++i) { ps[w][l][i] = best[i]; pi[w][l][i] = bidx[i]; }
    }
    __syncthreads();

    if (tid < 64) {
#pragma unroll 1
        for (int ww = 1; ww < 8; ++ww)
#pragma unroll
            for (int e = 0; e < 8; ++e) {
                float s = ps[ww][tid][e];
                if (s < best[7]) { int j = pi[ww][tid][e]; BINSERT(s, j); }
            }
        float q2 = fmaf(qx, qx, fmaf(qy, qy, qz * qz));
        float inv[8], ssum = 0.0f;
#pragma unroll
        for (int i = 0; i < 8; ++i) {
            float d2 = fmaf(2.0f, best[i], q2);
            float d  = sqrtf(fmaxf(d2, 0.0f)) + 1e-9f;
            inv[i] = 1.0f / d;
            ssum  += inv[i];
        }
        float rs = 1.0f / ssum;
#pragma unroll
        for (int i = 0; i < 8; ++i) {
            kidx[m * 8 + i] = bidx[i];
            kw[m * 8 + i]   = inv[i] * rs;
        }
    }
}

// One MLP layer on this wave's 32 rows, in-place in buf. A-frag: row=l&15(+16*rt),
// k=(l>>4)*8+j; B-frag preswizzled with the SAME (lane,j)->k map (k-perm cancels).
template <int KSTEPS, int NCT, bool RELU>
__device__ __forceinline__ void mlp_layer(_Float16 (*buf)[136],
                                          const _Float16* __restrict__ frag,
                                          const float* __restrict__ bias,
                                          int w, int l) {
    const int cl = l & 15, gl = l >> 4;
    f32x4 acc[2][NCT];
#pragma unroll
    for (int ct = 0; ct < NCT; ++ct) {
        float bv = bias[ct * 16 + cl];
#pragma unroll
        for (int rt = 0; rt < 2; ++rt) acc[rt][ct] = (f32x4){bv, bv, bv, bv};
    }
    const _Float16* fb = frag + (size_t)l * 8;
#pragma unroll 1
    for (int ks = 0; ks < KSTEPS; ++ks) {
        v8h a0 = *(const v8h*)&buf[w * 32 + cl][ks * 32 + gl * 8];
        v8h a1 = *(const v8h*)&buf[w * 32 + 16 + cl][ks * 32 + gl * 8];
#pragma unroll
        for (int ct = 0; ct < NCT; ++ct) {
            v8h bf = *(const v8h*)(fb + (size_t)(ks * NCT + ct) * 512);
            acc[0][ct] = __builtin_amdgcn_mfma_f32_16x16x32_f16(a0, bf, acc[0][ct], 0, 0, 0);
            acc[1][ct] = __builtin_amdgcn_mfma_f32_16x16x32_f16(a1, bf, acc[1][ct], 0, 0, 0);
        }
    }
    // C/D layout (m89-verified): row=(l>>4)*4+j, col=l&15
#pragma unroll
    for (int rt = 0; rt < 2; ++rt)
#pragma unroll
        for (int ct = 0; ct < NCT; ++ct)
#pragma unroll
            for (int j = 0; j < 4; ++j) {
                float v = acc[rt][ct][j];
                if (RELU) v = fmaxf(v, 0.0f);
                buf[w * 32 + rt * 16 + gl * 4 + j][ct * 16 + cl] = (_Float16)v;
            }
}

// Block = 128 rows (16 queries x 8 NB), 4 waves, each wave owns 32 rows.
// No __syncthreads anywhere: all LDS traffic is wave-private.
__global__ __launch_bounds__(256, 3) void mlp_kernel(
    const float* __restrict__ vf, const float4* __restrict__ vtx4,
    const float* __restrict__ qpts,
    const int* __restrict__ kidx, const float* __restrict__ kw,
    const _Float16* __restrict__ wfrag,
    const float* __restrict__ b0, const float* __restrict__ b1,
    const float* __restrict__ b2, const float* __restrict__ b3,
    float* __restrict__ out) {
    __shared__ _Float16 buf[128][136];   // 34.8 KB, stride 136 -> b128 reads 2-way (free)
    const int tid = threadIdx.x, w = tid >> 6, l = tid & 63;

    // ---- stage X = [feat(64) | q-v(3) | zeros..95] for rows w*32..w*32+31 ----
    {
        int h = l & 1;
        int lrow = w * 32 + (l >> 1);
        int grow = blockIdx.x * 128 + lrow;
        int q = grow >> 3;
        int idx = kidx[grow];
        const float4* src = (const float4*)(vf + (size_t)idx * DF) + h * 8;
#pragma unroll
        for (int t = 0; t < 4; ++t) {
            float4 a = src[2 * t], b = src[2 * t + 1];
            v8h pk = {(_Float16)a.x, (_Float16)a.y, (_Float16)a.z, (_Float16)a.w,
                      (_Float16)b.x, (_Float16)b.y, (_Float16)b.z, (_Float16)b.w};
            *(v8h*)&buf[lrow][h * 32 + t * 8] = pk;
        }
        v8h zz = {0, 0, 0, 0, 0, 0, 0, 0};
        if (h == 0) {
            float4 v = vtx4[idx];
            float qx = qpts[q * 3 + 0], qy = qpts[q * 3 + 1], qz = qpts[q * 3 + 2];
            v8h d = {(_Float16)(qx - v.x), (_Float16)(qy - v.y), (_Float16)(qz - v.z),
                     0, 0, 0, 0, 0};
            *(v8h*)&buf[lrow][64] = d;
            *(v8h*)&buf[lrow][88] = zz;
        } else {
            *(v8h*)&buf[lrow][72] = zz;
            *(v8h*)&buf[lrow][80] = zz;
        }
    }

    mlp_layer<3, 8, true>(buf, wfrag + 0,     b0, w, l);
    mlp_layer<4, 8, true>(buf, wfrag + 12288, b1, w, l);
    mlp_layer<4, 8, true>(buf, wfrag + 28672, b2, w, l);

    // ---- layer 3 (K=128 -> 64 cols) + inverse-distance weighting + 8-row reduce ----
    {
        const int cl = l & 15, gl = l >> 4;
        f32x4 acc[2][4];
#pragma unroll
        for (int ct = 0; ct < 4; ++ct) {
            float bv = b3[ct * 16 + cl];
#pragma unroll
            for (int rt = 0; rt < 2; ++rt) acc[rt][ct] = (f32x4){bv, bv, bv, bv};
        }
        const _Float16* fb = wfrag + 45056 + (size_t)l * 8;
#pragma unroll 1
        for (int ks = 0; ks < 4; ++ks) {
            v8h a0 = *(const v8h*)&buf[w * 32 + cl][ks * 32 + gl * 8];
            v8h a1 = *(const v8h*)&buf[w * 32 + 16 + cl][ks * 32 + gl * 8];
#pragma unroll
            for (int ct = 0; ct < 4; ++ct) {
                v8h bf = *(const v8h*)(fb + (size_t)(ks * 4 + ct) * 512);
                acc[0][ct] = __builtin_amdgcn_mfma_f32_16x16x32_f16(a0, bf, acc[0][ct], 0, 0, 0);
                acc[1][ct] = __builtin_amdgcn_mfma_f32_16x16x32_f16(a1, bf, acc[1][ct], 0, 0, 0);
            }
        }
        int GRbase = blockIdx.x * 128 + w * 32;
#pragma unroll
        for (int rt = 0; rt < 2; ++rt) {
            int r4 = GRbase + rt * 16 + gl * 4;       // first of this lane's 4 rows
            float4 kv = *(const float4*)&kw[r4];
#pragma unroll
            for (int ct = 0; ct < 4; ++ct) {
                float v = acc[rt][ct][0] * kv.x + acc[rt][ct][1] * kv.y +
                          acc[rt][ct][2] * kv.z + acc[rt][ct][3] * kv.w;
                v += __shfl_xor(v, 16);               // rows 0-3 + 4-7  (and 8-11 + 12-15)
                if ((gl & 1) == 0) {
                    int q = (GRbase + rt * 16 + ((gl == 2) ? 8 : 0)) >> 3;
                    out[(size_t)q * 64 + ct * 16 + cl] = v;
                }
            }
        }
    }
}

extern "C" void kernel_launch(void* const* d_in, const int* in_sizes, int n_in,
                              void* d_out, int out_size, void* d_ws, size_t ws_size,
                              hipStream_t stream) {
    const float* vtx = (const float*)d_in[0];
    const float* vf  = (const float*)d_in[1];
    const float* qp  = (const float*)d_in[2];
    const float* W0  = (const float*)d_in[3];
    const float* b0  = (const float*)d_in[4];
    const float* W1  = (const float*)d_in[5];
    const float* b1  = (const float*)d_in[6];
    const float* W2  = (const float*)d_in[7];
    const float* b2  = (const float*)d_in[8];
    const float* W3  = (const float*)d_in[9];
    const float* b3  = (const float*)d_in[10];
    float*       out = (float*)d_out;

    char*      ws    = (char*)d_ws;
    float4*    vtx4  = (float4*)(ws + VTX4_OFF);
    int*       kidx  = (int*)(ws + KIDX_OFF);
    float*     kw    = (float*)(ws + KW_OFF);
    _Float16*  wfrag = (_Float16*)(ws + WFRAG_OFF);

    hipLaunchKernelGGL(prep_kernel, dim3(27 + 208), dim3(256), 0, stream,
                       vtx, vtx4, W0, W1, W2, W3, wfrag);
    hipLaunchKernelGGL(knn_kernel, dim3(NQ / 64), dim3(512), 0, stream, vtx4, qp, kidx, kw);
    hipLaunchKernelGGL(mlp_kernel, dim3(NQ * 8 / 128), dim3(256), 0, stream,
                       vf, vtx4, qp, kidx, kw, wfrag, b0, b1, b2, b3, out);
}

// Round 8
// 191.829 us; speedup vs baseline: 10.6374x; 1.1908x over previous
//
#include <hip/hip_runtime.h>
#include <hip/hip_fp16.h>

#define NV    6890
#define NQ    32768
#define DF    64
#define DH    128
#define NW    16      // waves per knn block
#define CHUNK 431     // ceil(NV/NW)
#define CAPQ  12

typedef _Float16 v8h  __attribute__((ext_vector_type(8)));
typedef float    f32x4 __attribute__((ext_vector_type(4)));

// ---- workspace layout (bytes) ----
static constexpr size_t VTX4_OFF  = 0;                       // float4[6912]
static constexpr size_t KIDX_OFF  = 110592;
static constexpr size_t KW_OFF    = KIDX_OFF + (size_t)NQ * 8 * 4;   // 1159168
static constexpr size_t WFRAG_OFF = KW_OFF + (size_t)NQ * 8 * 4;     // 2207744
// wfrag (f16 elems): L0 @0 (12288), L1 @12288 (16384), L2 @28672 (16384), L3 @45056 (8192)

// Branchless sorted insert (ascending), ~40 VALU. Compares precomputed so
// updates use OLD neighbor values.
#define BINSERT(sv, jv) do {                                           \
    bool c0 = (sv) < best[0], c1 = (sv) < best[1],                     \
         c2 = (sv) < best[2], c3 = (sv) < best[3],                     \
         c4 = (sv) < best[4], c5 = (sv) < best[5],                     \
         c6 = (sv) < best[6], c7 = (sv) < best[7];                     \
    best[7] = c7 ? (c6 ? best[6] : (sv)) : best[7];                    \
    bidx[7] = c7 ? (c6 ? bidx[6] : (jv)) : bidx[7];                    \
    best[6] = c6 ? (c5 ? best[5] : (sv)) : best[6];                    \
    bidx[6] = c6 ? (c5 ? bidx[5] : (jv)) : bidx[6];                    \
    best[5] = c5 ? (c4 ? best[4] : (sv)) : best[5];                    \
    bidx[5] = c5 ? (c4 ? bidx[4] : (jv)) : bidx[5];                    \
    best[4] = c4 ? (c3 ? best[3] : (sv)) : best[4];                    \
    bidx[4] = c4 ? (c3 ? bidx[3] : (jv)) : bidx[4];                    \
    best[3] = c3 ? (c2 ? best[2] : (sv)) : best[3];                    \
    bidx[3] = c3 ? (c2 ? bidx[2] : (jv)) : bidx[3];                    \
    best[2] = c2 ? (c1 ? best[1] : (sv)) : best[2];                    \
    bidx[2] = c2 ? (c1 ? bidx[1] : (jv)) : bidx[2];                    \
    best[1] = c1 ? (c0 ? best[0] : (sv)) : best[1];                    \
    bidx[1] = c1 ? (c0 ? bidx[0] : (jv)) : bidx[1];                    \
    best[0] = c0 ? (sv) : best[0];                                     \
    bidx[0] = c0 ? (jv) : bidx[0];                                     \
} while (0)

// prep: pack vertices {x,y,z,0.5|v|^2} AND pre-swizzle weights into per-lane
// MFMA fragment order (f16). Fragment map: tile t=kt*NCT+ct, elem = t*512+lane*8+j,
// k = kt*32+(lane>>4)*8+j, col = ct*16+(lane&15).
__global__ void prep_kernel(const float* __restrict__ vtx, float4* __restrict__ vtx4,
                            const float* __restrict__ W0, const float* __restrict__ W1,
                            const float* __restrict__ W2, const float* __restrict__ W3,
                            _Float16* __restrict__ wfrag) {
    int b = blockIdx.x;
    if (b < 27) {
        int i = b * 256 + threadIdx.x;
        if (i < NV) {
            float x = vtx[i * 3 + 0], y = vtx[i * 3 + 1], z = vtx[i * 3 + 2];
            vtx4[i] = make_float4(x, y, z, 0.5f * (x * x + y * y + z * z));
        }
        return;
    }
    int e = (b - 27) * 256 + threadIdx.x;   // 0..53247
    const float* W; int base, NCT, C, KD;
    if      (e < 12288) { W = W0; base = 0;     NCT = 8; C = 128; KD = 67;  }
    else if (e < 28672) { W = W1; base = 12288; NCT = 8; C = 128; KD = 128; }
    else if (e < 45056) { W = W2; base = 28672; NCT = 8; C = 128; KD = 128; }
    else                { W = W3; base = 45056; NCT = 4; C = 64;  KD = 128; }
    int le = e - base;
    int t = le >> 9, r = le & 511;
    int lane = r >> 3, j = r & 7;
    int kt = t / NCT, ct = t % NCT;
    int k = kt * 32 + (lane >> 4) * 8 + j;
    int col = ct * 16 + (lane & 15);
    float v = (k < KD) ? W[k * C + col] : 0.0f;
    wfrag[e] = (_Float16)v;
}

__device__ __forceinline__ float vdist(const float4 v, float nqx, float nqy, float nqz) {
    float s = fmaf(nqx, v.x, v.w);
    s = fmaf(nqy, v.y, s);
    return fmaf(nqz, v.z, s);
}

// Exact two-phase KNN, 16-wave blocks for full occupancy.
// Block = 64 queries (1/lane) x 16 waves (vertex chunks of 431).
// Stage A: waves 0-7 only: 64-vertex prefix -> sorted per-lane top-8 -> LDS.
// Stage B: wave 0 only: merge the 8 lists (512-sample) -> exact T = 8th
//          smallest, broadcast via LDS; wave 0 keeps the merged seed.
// Scan:    all 16 waves filter their chunk by s<=T into per-lane u16 queue
//          (cap 12; overflow -> inline insert, still exact). Waves 0-7
//          exclude their prefix; waves 8-15 scan their full chunk.
// Drain:   batches of 4 (VGPR-lean). Final: log2 tree merge over 16 lists.
__global__ __launch_bounds__(1024, 8) void knn_kernel(const float4* __restrict__ vtx4,
                                                      const float* __restrict__ qpts,
                                                      int* __restrict__ kidx,
                                                      float* __restrict__ kw) {
    __shared__ float          ps[NW][64][9];    // 36864 B (pad 9: conflict-free)
    __shared__ unsigned short pi[NW][64][9];    // 18432 B
    __shared__ unsigned short qq[NW][64][CAPQ]; // 24576 B
    __shared__ float          Tl[64];
    const int tid = threadIdx.x, w = tid >> 6, l = tid & 63;
    const int m = blockIdx.x * 64 + l;
    const float qx = qpts[m * 3 + 0], qy = qpts[m * 3 + 1], qz = qpts[m * 3 + 2];
    const float nqx = -qx, nqy = -qy, nqz = -qz;

    float best[8]; int bidx[8];
#pragma unroll
    for (int i = 0; i < 8; ++i) { best[i] = 3.0e38f; bidx[i] = 0; }

    const int base = w * CHUNK;

    // ---- stage A (waves 0-7): prefix [base, base+64) ----
    if (w < 8) {
#pragma unroll 2
        for (int j = base; j < base + 64; ++j) {
            float s = vdist(vtx4[j], nqx, nqy, nqz);   // wave-uniform -> s_load
            BINSERT(s, j);
        }
#pragma unroll
        for (int i = 0; i < 8; ++i) {
            ps[w][l][i] = best[i];
            pi[w][l][i] = (unsigned short)bidx[i];
        }
    }
    __syncthreads();

    // ---- stage B (wave 0 only): merge 8 prefix lists -> T + seed ----
    if (w == 0) {
#pragma unroll 1
        for (int ww = 1; ww < 8; ++ww)
#pragma unroll
            for (int e = 0; e < 8; ++e) {
                float s = ps[ww][l][e];
                int   j = (int)pi[ww][l][e];
                BINSERT(s, j);
            }
        Tl[l] = best[7];
    }
    __syncthreads();
    const float T = Tl[l];

    if (w != 0) {
#pragma unroll
        for (int i = 0; i < 8; ++i) { best[i] = 3.0e38f; bidx[i] = 0; }
    }

    // ---- scan: filter survivors (s<=T) into per-lane queue ----
    int cnt = 0;
    const int j0 = (w < 8) ? base + 64 : base;
    const int j1 = (base + CHUNK < NV) ? base + CHUNK : NV;
#pragma unroll 2
    for (int j = j0; j < j1; ++j) {
        float s = vdist(vtx4[j], nqx, nqy, nqz);
        if (s <= T) {
            if (cnt < CAPQ) { qq[w][l][cnt] = (unsigned short)j; ++cnt; }
            else if (s < best[7]) { BINSERT(s, j); }   // overflow fallback (exact)
        }
    }

    // ---- drain queue in batches of 4 ----
    for (int b = 0; b < CAPQ; b += 4) {
        if (!__any(cnt > b)) break;
        int jj[4]; float4 vv[4];
#pragma unroll
        for (int t = 0; t < 4; ++t) {
            int qi = (b + t < cnt) ? (int)qq[w][l][b + t] : 0;
            jj[t] = qi; vv[t] = vtx4[qi];
        }
#pragma unroll
        for (int t = 0; t < 4; ++t) {
            float s = vdist(vv[t], nqx, nqy, nqz);
            s = (b + t < cnt) ? s : 3.0e38f;           // masked entries never insert
            BINSERT(s, jj[t]);
        }
    }

    // ---- publish scan lists (waves 1-15); wave 0 keeps seed+scan in regs ----
    if (w != 0) {
#pragma unroll
        for (int i = 0; i < 8; ++i) {
            ps[w][l][i] = best[i];
            pi[w][l][i] = (unsigned short)bidx[i];
        }
    }
    __syncthreads();

    // ---- tree merge: levels 8,4,2,1 ----
#pragma unroll 1
    for (int st = 8; st >= 1; st >>= 1) {
        if (w < st) {
#pragma unroll
            for (int e = 0; e < 8; ++e) {
                float s = ps[w + st][l][e];
                int   j = (int)pi[w + st][l][e];
                if (s < best[7]) { BINSERT(s, j); }
            }
            if (w != 0) {
#pragma unroll
                for (int i = 0; i < 8; ++i) {
                    ps[w][l][i] = best[i];
                    pi[w][l][i] = (unsigned short)bidx[i];
                }
            }
        }
        __syncthreads();
    }

    // ---- wave 0: weights + output ----
    if (w == 0) {
        float q2 = fmaf(qx, qx, fmaf(qy, qy, qz * qz));
        float inv[8], ssum = 0.0f;
#pragma unroll
        for (int i = 0; i < 8; ++i) {
            float d2 = fmaf(2.0f, best[i], q2);
            float d  = sqrtf(fmaxf(d2, 0.0f)) + 1e-9f;
            inv[i] = 1.0f / d;
            ssum  += inv[i];
        }
        float rs = 1.0f / ssum;
#pragma unroll
        for (int i = 0; i < 8; ++i) {
            kidx[m * 8 + i] = bidx[i];
            kw[m * 8 + i]   = inv[i] * rs;
        }
    }
}

// One MLP layer on this wave's 32 rows, in-place in buf. A-frag: row=l&15(+16*rt),
// k=(l>>4)*8+j; B-frag preswizzled with the SAME (lane,j)->k map (k-perm cancels).
template <int KSTEPS, int NCT, bool RELU>
__device__ __forceinline__ void mlp_layer(_Float16 (*buf)[136],
                                          const _Float16* __restrict__ frag,
                                          const float* __restrict__ bias,
                                          int w, int l) {
    const int cl = l & 15, gl = l >> 4;
    f32x4 acc[2][NCT];
#pragma unroll
    for (int ct = 0; ct < NCT; ++ct) {
        float bv = bias[ct * 16 + cl];
#pragma unroll
        for (int rt = 0; rt < 2; ++rt) acc[rt][ct] = (f32x4){bv, bv, bv, bv};
    }
    const _Float16* fb = frag + (size_t)l * 8;
#pragma unroll 1
    for (int ks = 0; ks < KSTEPS; ++ks) {
        v8h a0 = *(const v8h*)&buf[w * 32 + cl][ks * 32 + gl * 8];
        v8h a1 = *(const v8h*)&buf[w * 32 + 16 + cl][ks * 32 + gl * 8];
#pragma unroll
        for (int ct = 0; ct < NCT; ++ct) {
            v8h bf = *(const v8h*)(fb + (size_t)(ks * NCT + ct) * 512);
            acc[0][ct] = __builtin_amdgcn_mfma_f32_16x16x32_f16(a0, bf, acc[0][ct], 0, 0, 0);
            acc[1][ct] = __builtin_amdgcn_mfma_f32_16x16x32_f16(a1, bf, acc[1][ct], 0, 0, 0);
        }
    }
    // C/D layout (m89-verified): row=(l>>4)*4+j, col=l&15
#pragma unroll
    for (int rt = 0; rt < 2; ++rt)
#pragma unroll
        for (int ct = 0; ct < NCT; ++ct)
#pragma unroll
            for (int j = 0; j < 4; ++j) {
                float v = acc[rt][ct][j];
                if (RELU) v = fmaxf(v, 0.0f);
                buf[w * 32 + rt * 16 + gl * 4 + j][ct * 16 + cl] = (_Float16)v;
            }
}

// Block = 128 rows (16 queries x 8 NB), 4 waves, each wave owns 32 rows.
// No __syncthreads anywhere: all LDS traffic is wave-private.
__global__ __launch_bounds__(256, 3) void mlp_kernel(
    const float* __restrict__ vf, const float4* __restrict__ vtx4,
    const float* __restrict__ qpts,
    const int* __restrict__ kidx, const float* __restrict__ kw,
    const _Float16* __restrict__ wfrag,
    const float* __restrict__ b0, const float* __restrict__ b1,
    const float* __restrict__ b2, const float* __restrict__ b3,
    float* __restrict__ out) {
    __shared__ _Float16 buf[128][136];   // 34.8 KB, stride 136 -> b128 reads 2-way (free)
    const int tid = threadIdx.x, w = tid >> 6, l = tid & 63;

    // ---- stage X = [feat(64) | q-v(3) | zeros..95] for rows w*32..w*32+31 ----
    {
        int h = l & 1;
        int lrow = w * 32 + (l >> 1);
        int grow = blockIdx.x * 128 + lrow;
        int q = grow >> 3;
        int idx = kidx[grow];
        const float4* src = (const float4*)(vf + (size_t)idx * DF) + h * 8;
#pragma unroll
        for (int t = 0; t < 4; ++t) {
            float4 a = src[2 * t], b = src[2 * t + 1];
            v8h pk = {(_Float16)a.x, (_Float16)a.y, (_Float16)a.z, (_Float16)a.w,
                      (_Float16)b.x, (_Float16)b.y, (_Float16)b.z, (_Float16)b.w};
            *(v8h*)&buf[lrow][h * 32 + t * 8] = pk;
        }
        v8h zz = {0, 0, 0, 0, 0, 0, 0, 0};
        if (h == 0) {
            float4 v = vtx4[idx];
            float qx = qpts[q * 3 + 0], qy = qpts[q * 3 + 1], qz = qpts[q * 3 + 2];
            v8h d = {(_Float16)(qx - v.x), (_Float16)(qy - v.y), (_Float16)(qz - v.z),
                     0, 0, 0, 0, 0};
            *(v8h*)&buf[lrow][64] = d;
            *(v8h*)&buf[lrow][88] = zz;
        } else {
            *(v8h*)&buf[lrow][72] = zz;
            *(v8h*)&buf[lrow][80] = zz;
        }
    }

    mlp_layer<3, 8, true>(buf, wfrag + 0,     b0, w, l);
    mlp_layer<4, 8, true>(buf, wfrag + 12288, b1, w, l);
    mlp_layer<4, 8, true>(buf, wfrag + 28672, b2, w, l);

    // ---- layer 3 (K=128 -> 64 cols) + inverse-distance weighting + 8-row reduce ----
    {
        const int cl = l & 15, gl = l >> 4;
        f32x4 acc[2][4];
#pragma unroll
        for (int ct = 0; ct < 4; ++ct) {
            float bv = b3[ct * 16 + cl];
#pragma unroll
            for (int rt = 0; rt < 2; ++rt) acc[rt][ct] = (f32x4){bv, bv, bv, bv};
        }
        const _Float16* fb = wfrag + 45056 + (size_t)l * 8;
#pragma unroll 1
        for (int ks = 0; ks < 4; ++ks) {
            v8h a0 = *(const v8h*)&buf[w * 32 + cl][ks * 32 + gl * 8];
            v8h a1 = *(const v8h*)&buf[w * 32 + 16 + cl][ks * 32 + gl * 8];
#pragma unroll
            for (int ct = 0; ct < 4; ++ct) {
                v8h bf = *(const v8h*)(fb + (size_t)(ks * 4 + ct) * 512);
                acc[0][ct] = __builtin_amdgcn_mfma_f32_16x16x32_f16(a0, bf, acc[0][ct], 0, 0, 0);
                acc[1][ct] = __builtin_amdgcn_mfma_f32_16x16x32_f16(a1, bf, acc[1][ct], 0, 0, 0);
            }
        }
        int GRbase = blockIdx.x * 128 + w * 32;
#pragma unroll
        for (int rt = 0; rt < 2; ++rt) {
            int r4 = GRbase + rt * 16 + gl * 4;       // first of this lane's 4 rows
            float4 kv = *(const float4*)&kw[r4];
#pragma unroll
            for (int ct = 0; ct < 4; ++ct) {
                float v = acc[rt][ct][0] * kv.x + acc[rt][ct][1] * kv.y +
                          acc[rt][ct][2] * kv.z + acc[rt][ct][3] * kv.w;
                v += __shfl_xor(v, 16);               // rows 0-3 + 4-7  (and 8-11 + 12-15)
                if ((gl & 1) == 0) {
                    int q = (GRbase + rt * 16 + ((gl == 2) ? 8 : 0)) >> 3;
                    out[(size_t)q * 64 + ct * 16 + cl] = v;
                }
            }
        }
    }
}

extern "C" void kernel_launch(void* const* d_in, const int* in_sizes, int n_in,
                              void* d_out, int out_size, void* d_ws, size_t ws_size,
                              hipStream_t stream) {
    const float* vtx = (const float*)d_in[0];
    const float* vf  = (const float*)d_in[1];
    const float* qp  = (const float*)d_in[2];
    const float* W0  = (const float*)d_in[3];
    const float* b0  = (const float*)d_in[4];
    const float* W1  = (const float*)d_in[5];
    const float* b1  = (const float*)d_in[6];
    const float* W2  = (const float*)d_in[7];
    const float* b2  = (const float*)d_in[8];
    const float* W3  = (const float*)d_in[9];
    const float* b3  = (const float*)d_in[10];
    float*       out = (float*)d_out;

    char*      ws    = (char*)d_ws;
    float4*    vtx4  = (float4*)(ws + VTX4_OFF);
    int*       kidx  = (int*)(ws + KIDX_OFF);
    float*     kw    = (float*)(ws + KW_OFF);
    _Float16*  wfrag = (_Float16*)(ws + WFRAG_OFF);

    hipLaunchKernelGGL(prep_kernel, dim3(27 + 208), dim3(256), 0, stream,
                       vtx, vtx4, W0, W1, W2, W3, wfrag);
    hipLaunchKernelGGL(knn_kernel, dim3(NQ / 64), dim3(1024), 0, stream, vtx4, qp, kidx, kw);
    hipLaunchKernelGGL(mlp_kernel, dim3(NQ * 8 / 128), dim3(256), 0, stream,
                       vf, vtx4, qp, kidx, kw, wfrag, b0, b1, b2, b3, out);
}